// Round 3
// baseline (293.622 us; speedup 1.0000x reference)
//
#include <hip/hip_runtime.h>
#include <hip/hip_bf16.h>

// Problem: AdvancedAttentionLayer  B=2, S=2048, D=1024, H=16, DH=64
// Round 14: attn_kernel rewritten around mfma_f32_32x32x16_bf16.
// Round-13 counters showed the kernel was LDS-pipe-bound (~4200 LDS
// cycles/CU/iter vs 5250 total; MfmaUtil stuck at 22% while occupancy
// doubled). This version: (a) 32x32 MFMA, 32 q/wave -> 2x FLOP per LDS
// byte and half the MFMA instrs; (b) K/V/mask fragments read DIRECTLY
// from global (L1/L2-resident, 4 waves/block hit identical addresses)
// -> no k_lds/vt_lds, no gl_lds staging, NO barriers in the loop;
// (c) LDS only holds the wave-private P bounce (XOR-swizzled 16B
// chunks, conflict-free, double-buffered by iteration parity);
// (d) denominator via one 32x32 MFMA per k-step with broadcast mask
// B-frag. Prep/proj kernels unchanged.

#define B_  2
#define S_  2048
#define D_  1024
#define K_  1024
#define H_  16
#define DH_ 64
#define BS_ (B_*S_)

typedef __hip_bfloat16 bf16;
typedef __attribute__((ext_vector_type(8))) short s8v;    // 8 bf16 = 4 VGPRs
typedef __attribute__((ext_vector_type(4))) short s4v;    // 4 bf16
typedef __attribute__((ext_vector_type(4))) float f4v;    // 16x16 MFMA C/D
typedef __attribute__((ext_vector_type(16))) float f16v;  // 32x32 MFMA C/D

__device__ __forceinline__ float b2f(bf16 x) { return __bfloat162float(x); }
__device__ __forceinline__ bf16  f2b(float x) { return __float2bfloat16(x); }

__device__ __forceinline__ void gl_lds_16B(const bf16* g, bf16* l) {
    __builtin_amdgcn_global_load_lds(
        (const __attribute__((address_space(1))) unsigned int*)g,
        (__attribute__((address_space(3))) unsigned int*)l, 16, 0, 0);
}

// 0.125 * log2(e): folded QK^T scale so softmax uses raw exp2
#define QSCALE_ 0.1803368801f

// ---------------------------------------------------------------------------
// Fused prep kernel. Grid 5136 blocks x 256:
//   blocks [0,1024):    W transpose, z = blk>>8 (Wq/Wk/Wv/Wo), 64x64 tiles
//   blocks [1024,5120): X fp32 -> bf16, 1024 elems per block
//   blocks [5120,5136): mask int32 -> bf16 0/1
// ---------------------------------------------------------------------------
__global__ __launch_bounds__(256) void prep_kernel(
    const float* __restrict__ X, const int* __restrict__ mask,
    const float* __restrict__ Wq, const float* __restrict__ Wk,
    const float* __restrict__ Wv, const float* __restrict__ Wo,
    bf16* __restrict__ Xb, bf16* __restrict__ mkbf,
    bf16* __restrict__ WTq, bf16* __restrict__ WTk,
    bf16* __restrict__ WTv, bf16* __restrict__ WTo)
{
    __shared__ float Ls[64][68];
    const int blk = blockIdx.x;
    const int t   = threadIdx.x;

    if (blk < 1024) {
        const int z   = blk >> 8;
        const int t16 = blk & 255;
        const int k0  = (t16 >> 4) * 64;
        const int n0  = (t16 & 15) * 64;
        const float* __restrict__ W = (z == 0) ? Wq : (z == 1) ? Wk : (z == 2) ? Wv : Wo;
        bf16* __restrict__ WT       = (z == 0) ? WTq : (z == 1) ? WTk : (z == 2) ? WTv : WTo;

        const int lr = t >> 4;
        const int lc = (t & 15) * 4;
        #pragma unroll
        for (int i = 0; i < 4; i++) {
            const int k = i * 16 + lr;
            const float4 v = *(const float4*)(W + (size_t)(k0 + k) * K_ + n0 + lc);
            Ls[k][lc + 0] = v.x; Ls[k][lc + 1] = v.y;
            Ls[k][lc + 2] = v.z; Ls[k][lc + 3] = v.w;
        }
        __syncthreads();
        #pragma unroll
        for (int i = 0; i < 4; i++) {
            const int n = i * 16 + lr;
            s4v o;
            #pragma unroll
            for (int j = 0; j < 4; j++) {
                bf16 tb = f2b(Ls[lc + j][n]);
                o[j] = *(short*)&tb;
            }
            *(s4v*)(WT + (size_t)(n0 + n) * K_ + k0 + lc) = o;
        }
    } else if (blk < 5120) {
        const size_t idx = ((size_t)(blk - 1024) * 256 + t) * 4;
        const float4 v = *(const float4*)(X + idx);
        bf16 t0 = f2b(v.x), t1 = f2b(v.y), t2 = f2b(v.z), t3 = f2b(v.w);
        s4v o;
        o[0] = *(short*)&t0; o[1] = *(short*)&t1;
        o[2] = *(short*)&t2; o[3] = *(short*)&t3;
        *(s4v*)(Xb + idx) = o;
    } else {
        const int idx = (blk - 5120) * 256 + t;
        mkbf[idx] = f2b(mask[idx] ? 1.0f : 0.0f);
    }
}

// ---------------------------------------------------------------------------
// MFMA GEMM core, 128x128 tile (m97 structure). SWAPPED -> C^T layout.
// ---------------------------------------------------------------------------
template <bool SWAPPED>
__device__ __forceinline__ void gemm_tile(
    const bf16* __restrict__ A, const bf16* __restrict__ BT,
    int m0, int n0, bf16* As, bf16* Bs, f4v acc[4][4])
{
    const int t    = threadIdx.x;
    const int lane = t & 63;
    const int wave = t >> 6;
    const int quad = lane >> 4;
    const int l15  = lane & 15;
    const int wr   = wave >> 1;
    const int wc   = wave & 1;

    const int sr = t >> 3;
    const int sc = (t & 7) * 8;

    for (int kb = 0; kb < K_; kb += 64) {
        #pragma unroll
        for (int i = 0; i < 4; i++) {
            const int r = i * 32 + sr;
            gl_lds_16B(A  + (size_t)(m0 + r) * K_ + kb + sc, As + r * 64 + sc);
            gl_lds_16B(BT + (size_t)(n0 + r) * K_ + kb + sc, Bs + r * 64 + sc);
        }
        __syncthreads();

        #pragma unroll
        for (int ks = 0; ks < 2; ks++) {
            s8v fA[4], fB[4];
            #pragma unroll
            for (int i = 0; i < 4; i++) {
                fA[i] = *(const s8v*)&As[(wr * 64 + i * 16 + l15) * 64 + ks * 32 + quad * 8];
                fB[i] = *(const s8v*)&Bs[(wc * 64 + i * 16 + l15) * 64 + ks * 32 + quad * 8];
            }
            #pragma unroll
            for (int i = 0; i < 4; i++)
                #pragma unroll
                for (int j = 0; j < 4; j++)
                    acc[i][j] = SWAPPED
                        ? __builtin_amdgcn_mfma_f32_16x16x32_bf16(fB[i], fA[j], acc[i][j], 0, 0, 0)
                        : __builtin_amdgcn_mfma_f32_16x16x32_bf16(fA[i], fB[j], acc[i][j], 0, 0, 0);
        }
        __syncthreads();
    }
}

// ---------------------------------------------------------------------------
// QKV projection via MFMA. Grid (32, 8, 3), block 256.
// ---------------------------------------------------------------------------
__global__ __launch_bounds__(256) void proj_qkv_kernel(
    const bf16* __restrict__ Xb,
    const bf16* __restrict__ WTq, const float* __restrict__ bq,
    const bf16* __restrict__ WTk, const float* __restrict__ bk,
    const bf16* __restrict__ WTv, const float* __restrict__ bv,
    const float* __restrict__ emo, const int* __restrict__ mask,
    bf16* __restrict__ q_ws, bf16* __restrict__ k_ws, bf16* __restrict__ v_ws)
{
    const int m0 = blockIdx.x * 128;
    const int n0 = blockIdx.y * 128;
    const int z  = blockIdx.z;

    __shared__ __align__(16) bf16 As[128 * 64];
    __shared__ __align__(16) bf16 Bs[128 * 64];

    const int t    = threadIdx.x;
    const int lane = t & 63;
    const int wave = t >> 6;
    const int quad = lane >> 4;
    const int l15  = lane & 15;
    const int wr   = wave >> 1;
    const int wc   = wave & 1;

    f4v acc[4][4] = {};

    if (z == 0) {
        gemm_tile<false>(Xb, WTq, m0, n0, As, Bs, acc);
        #pragma unroll
        for (int j = 0; j < 4; j++) {
            const int n  = n0 + wc * 64 + j * 16 + l15;
            const int h  = n >> 6, dh = n & 63;
            const float bias_n = bq[n] + emo[n];
            #pragma unroll
            for (int i = 0; i < 4; i++) {
                #pragma unroll
                for (int r = 0; r < 4; r++) {
                    const int m = m0 + wr * 64 + i * 16 + quad * 4 + r;
                    const int b = m >> 11, s = m & 2047;
                    q_ws[(((size_t)(b * H_ + h)) * S_ + s) * DH_ + dh] =
                        f2b((acc[i][j][r] + bias_n) * QSCALE_);
                }
            }
        }
    } else if (z == 1) {
        gemm_tile<false>(Xb, WTk, m0, n0, As, Bs, acc);
        #pragma unroll
        for (int j = 0; j < 4; j++) {
            const int n  = n0 + wc * 64 + j * 16 + l15;
            const int h  = n >> 6, dh = n & 63;
            const float bias_n = bk[n];
            #pragma unroll
            for (int i = 0; i < 4; i++) {
                #pragma unroll
                for (int r = 0; r < 4; r++) {
                    const int m = m0 + wr * 64 + i * 16 + quad * 4 + r;
                    const int b = m >> 11, s = m & 2047;
                    k_ws[(((size_t)(b * H_ + h)) * S_ + s) * DH_ + dh] =
                        f2b(acc[i][j][r] + bias_n);
                }
            }
        }
    } else {
        gemm_tile<true>(Xb, WTv, m0, n0, As, Bs, acc);
        #pragma unroll
        for (int j = 0; j < 4; j++) {
            const int m = m0 + wr * 64 + j * 16 + l15;
            const int b = m >> 11, s = m & 2047;
            const float msk = mask[b * S_ + s] ? 1.0f : 0.0f;
            #pragma unroll
            for (int i = 0; i < 4; i++) {
                #pragma unroll
                for (int r = 0; r < 4; r++) {
                    const int n  = n0 + wc * 64 + i * 16 + quad * 4 + r;
                    const int h  = n >> 6, dh = n & 63;
                    v_ws[(((size_t)(b * H_ + h)) * DH_ + dh) * S_ + s] =
                        f2b((acc[i][j][r] + bv[n]) * msk);
                }
            }
        }
    }
}

// ---------------------------------------------------------------------------
// Output projection: 128x128 tile, grid (32, 8). out = ctx @ Wo + bo (fp32).
// ---------------------------------------------------------------------------
__global__ __launch_bounds__(256) void proj_out_kernel(
    const bf16* __restrict__ ctx, const bf16* __restrict__ WTo,
    const float* __restrict__ bo, float* __restrict__ out)
{
    const int m0 = blockIdx.x * 128;
    const int n0 = blockIdx.y * 128;

    __shared__ __align__(16) bf16 As[128 * 64];
    __shared__ __align__(16) bf16 Bs[128 * 64];

    const int t    = threadIdx.x;
    const int lane = t & 63;
    const int wave = t >> 6;
    const int quad = lane >> 4;
    const int l15  = lane & 15;
    const int wr   = wave >> 1;
    const int wc   = wave & 1;

    f4v acc[4][4] = {};
    gemm_tile<false>(ctx, WTo, m0, n0, As, Bs, acc);

    #pragma unroll
    for (int j = 0; j < 4; j++) {
        const int n = n0 + wc * 64 + j * 16 + l15;
        const float bias_n = bo[n];
        #pragma unroll
        for (int i = 0; i < 4; i++) {
            #pragma unroll
            for (int r = 0; r < 4; r++) {
                const int m = m0 + wr * 64 + i * 16 + quad * 4 + r;
                out[(size_t)m * D_ + n] = acc[i][j][r] + bias_n;
            }
        }
    }
}

// ---------------------------------------------------------------------------
// MFMA flash attention (round-14): 32x32x16 MFMA, 32 q-rows per wave,
// 4 waves x 256 threads, grid (B*H=32, S/128=16). K/V/mask fragments read
// directly from global (L1/L2-hot); LDS holds only the wave-private P
// bounce (XOR-swizzled, double-buffered by iteration parity). No barriers.
//
// Layouts (verified mappings):
//   C/D 32x32: col = lane&31, row = (reg&3) + 8*(reg>>2) + 4*(lane>>5)
//   A 32x16:   row = lane&31, k = (lane>>5)*8 + j   (8 bf16 = one b128)
//   B 16x32:   col = lane&31, k = (lane>>5)*8 + j
// ---------------------------------------------------------------------------
#define PQ_ 2048   // per-wave P buffer elems (32 q x 64 keys)

__global__ __launch_bounds__(256) void attn_kernel(
    const bf16* __restrict__ q_ws, const bf16* __restrict__ k_ws,
    const bf16* __restrict__ v_ws, const bf16* __restrict__ mkbf,
    bf16* __restrict__ ctx)
{
    const int bh = blockIdx.x;
    const int q0 = blockIdx.y * 128;
    const int b  = bh >> 4;
    const int h  = bh & 15;

    __shared__ __align__(16) bf16 p_lds[2 * 4 * PQ_];   // [parity][wave][32*64]

    const int t    = threadIdx.x;
    const int wave = t >> 6;
    const int lane = t & 63;
    const int ql   = lane & 31;      // q col (C) / key row (A) / dh col (B)
    const int hf   = lane >> 5;      // lane half
    const int swz  = ql & 7;         // XOR swizzle on 16B chunks

    // ---- Q as B-operand frags: q = q0 + wave*32 + ql, d = kd*16 + hf*8 ----
    s8v qf[4];
    #pragma unroll
    for (int kd = 0; kd < 4; kd++)
        qf[kd] = *(const s8v*)(q_ws +
            ((size_t)bh * S_ + q0 + wave * 32 + ql) * DH_ + kd * 16 + hf * 8);

    f16v oacc[2] = {};   // [dh-tile]: 16 q-rows per lane (C layout)
    f16v osum    = {};   // denominator, same reg->q mapping

    const bf16* __restrict__ kbase = k_ws + (size_t)bh * S_ * DH_;
    const bf16* __restrict__ vbase = v_ws + (size_t)bh * DH_ * S_;
    const bf16* __restrict__ mbase = mkbf + (size_t)b * S_;

    int parity = 0;
    for (int kb0 = 0; kb0 < S_; kb0 += 64, parity ^= 1) {
        bf16* __restrict__ pb = p_lds + parity * (4 * PQ_) + wave * PQ_;

        // ---- S^T tiles: sacc[kt] = K[kt] . Q^T  (A=K rows=key, B=Q cols=q)
        f16v sacc[2] = {};
        __builtin_amdgcn_s_setprio(1);
        #pragma unroll
        for (int kt = 0; kt < 2; kt++) {
            #pragma unroll
            for (int kd = 0; kd < 4; kd++) {
                const s8v kf = *(const s8v*)(kbase +
                    (size_t)(kb0 + kt * 32 + ql) * DH_ + kd * 16 + hf * 8);
                sacc[kt] = __builtin_amdgcn_mfma_f32_32x32x16_bf16(kf, qf[kd], sacc[kt], 0, 0, 0);
            }
        }
        __builtin_amdgcn_s_setprio(0);

        // ---- p = exp2(s) -> bf16 pairs -> wave-private LDS (swizzled) ----
        // Lane holds q=ql, keys kt*32 + (r&3) + 8*(r>>2) + 4*hf. Regs 4g..4g+3
        // are keys 8g+4hf..+3: one aligned 8B (4 bf16) chunk-quarter.
        #pragma unroll
        for (int kt = 0; kt < 2; kt++) {
            #pragma unroll
            for (int g = 0; g < 4; g++) {
                float2 e01, e23;
                e01.x = exp2f(sacc[kt][4 * g + 0]);
                e01.y = exp2f(sacc[kt][4 * g + 1]);
                e23.x = exp2f(sacc[kt][4 * g + 2]);
                e23.y = exp2f(sacc[kt][4 * g + 3]);
                union { __hip_bfloat162 hh; unsigned u; } lo, hi;
                lo.hh = __float22bfloat162_rn(e01);
                hi.hh = __float22bfloat162_rn(e23);
                *(uint2*)&pb[ql * 64 + ((kt * 4 + g) ^ swz) * 8 + hf * 4] =
                    make_uint2(lo.u, hi.u);
            }
        }
        // wave-private LDS RAW: compiler inserts the lgkm waits; parity
        // double-buffer breaks the cross-iteration WAR chain.

        // ---- O += P.V ; denom += P.mask  (A=P rows=q; B from global) ----
        #pragma unroll
        for (int ks = 0; ks < 4; ks++) {
            const s8v pf = *(const s8v*)&pb[ql * 64 + ((2 * ks + hf) ^ swz) * 8];
            const s8v mf = *(const s8v*)(mbase + kb0 + ks * 16 + hf * 8);
            __builtin_amdgcn_s_setprio(1);
            osum = __builtin_amdgcn_mfma_f32_32x32x16_bf16(pf, mf, osum, 0, 0, 0);
            #pragma unroll
            for (int dt = 0; dt < 2; dt++) {
                const s8v vf = *(const s8v*)(vbase +
                    (size_t)(dt * 32 + ql) * S_ + kb0 + ks * 16 + hf * 8);
                oacc[dt] = __builtin_amdgcn_mfma_f32_32x32x16_bf16(pf, vf, oacc[dt], 0, 0, 0);
            }
            __builtin_amdgcn_s_setprio(0);
        }
    }

    // ---- epilogue: reg r -> q row (r&3)+8*(r>>2)+4*hf; lane col ql = dh ----
    #pragma unroll
    for (int r = 0; r < 16; r++) {
        const float inv = 1.0f / osum[r];
        const int q = q0 + wave * 32 + (r & 3) + 8 * (r >> 2) + 4 * hf;
        #pragma unroll
        for (int dt = 0; dt < 2; dt++)
            ctx[((size_t)b * S_ + q) * D_ + h * DH_ + dt * 32 + ql] =
                f2b(oacc[dt][r] * inv);
    }
}

// ---------------------------------------------------------------------------
extern "C" void kernel_launch(void* const* d_in, const int* in_sizes, int n_in,
                              void* d_out, int out_size, void* d_ws, size_t ws_size,
                              hipStream_t stream) {
    (void)in_sizes; (void)n_in; (void)out_size; (void)ws_size;

    const float* X    = (const float*)d_in[0];
    const int*   mask = (const int*)d_in[1];
    const float* Wq   = (const float*)d_in[2];
    const float* bq   = (const float*)d_in[3];
    const float* Wk   = (const float*)d_in[4];
    const float* bk   = (const float*)d_in[5];
    const float* Wv   = (const float*)d_in[6];
    const float* bv   = (const float*)d_in[7];
    const float* emo  = (const float*)d_in[8];
    const float* Wo   = (const float*)d_in[9];
    const float* bo   = (const float*)d_in[10];
    float* out = (float*)d_out;

    bf16* q_ws = (bf16*)d_ws;                       // [B,H,S,DH]   8 MB
    bf16* k_ws = q_ws + (size_t)BS_ * D_;           // [B,H,S,DH]   8 MB
    bf16* v_ws = k_ws + (size_t)BS_ * D_;           // [B,H,DH,S]   8 MB
    bf16* ctx  = v_ws + (size_t)BS_ * D_;           // [B,S,D]      8 MB
    bf16* Xb   = ctx  + (size_t)BS_ * D_;           // [BS,D]       8 MB
    bf16* WTq  = Xb   + (size_t)BS_ * D_;           // [N,K]        2 MB
    bf16* WTk  = WTq  + (size_t)D_ * K_;
    bf16* WTv  = WTk  + (size_t)D_ * K_;
    bf16* WTo  = WTv  + (size_t)D_ * K_;
    bf16* mkbf = WTo  + (size_t)D_ * K_;            // [B*S] bf16 mask

    hipLaunchKernelGGL(prep_kernel, dim3(5136), dim3(256), 0, stream,
                       X, mask, Wq, Wk, Wv, Wo, Xb, mkbf, WTq, WTk, WTv, WTo);
    hipLaunchKernelGGL(proj_qkv_kernel, dim3(BS_ / 128, D_ / 128, 3), dim3(256), 0, stream,
                       Xb, WTq, bq, WTk, bk, WTv, bv, emo, mask, q_ws, k_ws, v_ws);
    hipLaunchKernelGGL(attn_kernel, dim3(B_ * H_, S_ / 128), dim3(256), 0, stream,
                       q_ws, k_ws, v_ws, mkbf, ctx);
    hipLaunchKernelGGL(proj_out_kernel, dim3(BS_ / 128, D_ / 128), dim3(256), 0, stream,
                       ctx, WTo, bo, out);
}

// Round 4
// 234.168 us; speedup vs baseline: 1.2539x; 1.2539x over previous
//
#include <hip/hip_runtime.h>
#include <hip/hip_bf16.h>

// Problem: AdvancedAttentionLayer  B=2, S=2048, D=1024, H=16, DH=64
// Round 15: attn = 32x32x16 MFMA + LDS-staged K/V (dbuf, 1 barrier/iter)
// + T12 in-register P exchange (cvt_pk_bf16 + permlane32_swap) replacing
// the p_lds bounce. r12-r14 counters showed ALL 3.1M bank-conflict cycles
// came from p_lds stores (524288 stores x 6 cyc in every round), and r14
// showed direct-global fragments are latency-death. This keeps K/V frags
// in LDS (r12-style swizzled staging) and keeps P entirely in registers:
// lane ql and ql+32 hold the same q column, so permlane32_swap assembles
// the PV A-fragment from the QK^T C-layout. Prep/proj unchanged.

#define B_  2
#define S_  2048
#define D_  1024
#define K_  1024
#define H_  16
#define DH_ 64
#define BS_ (B_*S_)

typedef __hip_bfloat16 bf16;
typedef __attribute__((ext_vector_type(8))) short s8v;    // 8 bf16 = 4 VGPRs
typedef __attribute__((ext_vector_type(4))) short s4v;    // 4 bf16
typedef __attribute__((ext_vector_type(4))) float f4v;    // 16x16 MFMA C/D
typedef __attribute__((ext_vector_type(16))) float f16v;  // 32x32 MFMA C/D

__device__ __forceinline__ float b2f(bf16 x) { return __bfloat162float(x); }
__device__ __forceinline__ bf16  f2b(float x) { return __float2bfloat16(x); }

__device__ __forceinline__ void gl_lds_16B(const bf16* g, bf16* l) {
    __builtin_amdgcn_global_load_lds(
        (const __attribute__((address_space(1))) unsigned int*)g,
        (__attribute__((address_space(3))) unsigned int*)l, 16, 0, 0);
}

// pack two f32 -> two bf16 in one dword (low = a)
__device__ __forceinline__ unsigned cvtpk_bf16(float a, float b) {
    unsigned r;
    asm("v_cvt_pk_bf16_f32 %0, %1, %2" : "=v"(r) : "v"(a), "v"(b));
    return r;
}
// swap hi-half lanes of a with lo-half lanes of b (lane i <-> lane i+32)
__device__ __forceinline__ void plswap(unsigned &a, unsigned &b) {
    asm("v_permlane32_swap_b32 %0, %1" : "+v"(a), "+v"(b));
}

// 0.125 * log2(e): folded QK^T scale so softmax uses raw exp2
#define QSCALE_ 0.1803368801f

// ---------------------------------------------------------------------------
// Fused prep kernel. Grid 5136 blocks x 256:
//   blocks [0,1024):    W transpose, z = blk>>8 (Wq/Wk/Wv/Wo), 64x64 tiles
//   blocks [1024,5120): X fp32 -> bf16, 1024 elems per block
//   blocks [5120,5136): mask int32 -> bf16 0/1
// ---------------------------------------------------------------------------
__global__ __launch_bounds__(256) void prep_kernel(
    const float* __restrict__ X, const int* __restrict__ mask,
    const float* __restrict__ Wq, const float* __restrict__ Wk,
    const float* __restrict__ Wv, const float* __restrict__ Wo,
    bf16* __restrict__ Xb, bf16* __restrict__ mkbf,
    bf16* __restrict__ WTq, bf16* __restrict__ WTk,
    bf16* __restrict__ WTv, bf16* __restrict__ WTo)
{
    __shared__ float Ls[64][68];
    const int blk = blockIdx.x;
    const int t   = threadIdx.x;

    if (blk < 1024) {
        const int z   = blk >> 8;
        const int t16 = blk & 255;
        const int k0  = (t16 >> 4) * 64;
        const int n0  = (t16 & 15) * 64;
        const float* __restrict__ W = (z == 0) ? Wq : (z == 1) ? Wk : (z == 2) ? Wv : Wo;
        bf16* __restrict__ WT       = (z == 0) ? WTq : (z == 1) ? WTk : (z == 2) ? WTv : WTo;

        const int lr = t >> 4;
        const int lc = (t & 15) * 4;
        #pragma unroll
        for (int i = 0; i < 4; i++) {
            const int k = i * 16 + lr;
            const float4 v = *(const float4*)(W + (size_t)(k0 + k) * K_ + n0 + lc);
            Ls[k][lc + 0] = v.x; Ls[k][lc + 1] = v.y;
            Ls[k][lc + 2] = v.z; Ls[k][lc + 3] = v.w;
        }
        __syncthreads();
        #pragma unroll
        for (int i = 0; i < 4; i++) {
            const int n = i * 16 + lr;
            s4v o;
            #pragma unroll
            for (int j = 0; j < 4; j++) {
                bf16 tb = f2b(Ls[lc + j][n]);
                o[j] = *(short*)&tb;
            }
            *(s4v*)(WT + (size_t)(n0 + n) * K_ + k0 + lc) = o;
        }
    } else if (blk < 5120) {
        const size_t idx = ((size_t)(blk - 1024) * 256 + t) * 4;
        const float4 v = *(const float4*)(X + idx);
        bf16 t0 = f2b(v.x), t1 = f2b(v.y), t2 = f2b(v.z), t3 = f2b(v.w);
        s4v o;
        o[0] = *(short*)&t0; o[1] = *(short*)&t1;
        o[2] = *(short*)&t2; o[3] = *(short*)&t3;
        *(s4v*)(Xb + idx) = o;
    } else {
        const int idx = (blk - 5120) * 256 + t;
        mkbf[idx] = f2b(mask[idx] ? 1.0f : 0.0f);
    }
}

// ---------------------------------------------------------------------------
// MFMA GEMM core, 128x128 tile (m97 structure). SWAPPED -> C^T layout.
// ---------------------------------------------------------------------------
template <bool SWAPPED>
__device__ __forceinline__ void gemm_tile(
    const bf16* __restrict__ A, const bf16* __restrict__ BT,
    int m0, int n0, bf16* As, bf16* Bs, f4v acc[4][4])
{
    const int t    = threadIdx.x;
    const int lane = t & 63;
    const int wave = t >> 6;
    const int quad = lane >> 4;
    const int l15  = lane & 15;
    const int wr   = wave >> 1;
    const int wc   = wave & 1;

    const int sr = t >> 3;
    const int sc = (t & 7) * 8;

    for (int kb = 0; kb < K_; kb += 64) {
        #pragma unroll
        for (int i = 0; i < 4; i++) {
            const int r = i * 32 + sr;
            gl_lds_16B(A  + (size_t)(m0 + r) * K_ + kb + sc, As + r * 64 + sc);
            gl_lds_16B(BT + (size_t)(n0 + r) * K_ + kb + sc, Bs + r * 64 + sc);
        }
        __syncthreads();

        #pragma unroll
        for (int ks = 0; ks < 2; ks++) {
            s8v fA[4], fB[4];
            #pragma unroll
            for (int i = 0; i < 4; i++) {
                fA[i] = *(const s8v*)&As[(wr * 64 + i * 16 + l15) * 64 + ks * 32 + quad * 8];
                fB[i] = *(const s8v*)&Bs[(wc * 64 + i * 16 + l15) * 64 + ks * 32 + quad * 8];
            }
            #pragma unroll
            for (int i = 0; i < 4; i++)
                #pragma unroll
                for (int j = 0; j < 4; j++)
                    acc[i][j] = SWAPPED
                        ? __builtin_amdgcn_mfma_f32_16x16x32_bf16(fB[i], fA[j], acc[i][j], 0, 0, 0)
                        : __builtin_amdgcn_mfma_f32_16x16x32_bf16(fA[i], fB[j], acc[i][j], 0, 0, 0);
        }
        __syncthreads();
    }
}

// ---------------------------------------------------------------------------
// QKV projection via MFMA. Grid (32, 8, 3), block 256.
// ---------------------------------------------------------------------------
__global__ __launch_bounds__(256) void proj_qkv_kernel(
    const bf16* __restrict__ Xb,
    const bf16* __restrict__ WTq, const float* __restrict__ bq,
    const bf16* __restrict__ WTk, const float* __restrict__ bk,
    const bf16* __restrict__ WTv, const float* __restrict__ bv,
    const float* __restrict__ emo, const int* __restrict__ mask,
    bf16* __restrict__ q_ws, bf16* __restrict__ k_ws, bf16* __restrict__ v_ws)
{
    const int m0 = blockIdx.x * 128;
    const int n0 = blockIdx.y * 128;
    const int z  = blockIdx.z;

    __shared__ __align__(16) bf16 As[128 * 64];
    __shared__ __align__(16) bf16 Bs[128 * 64];

    const int t    = threadIdx.x;
    const int lane = t & 63;
    const int wave = t >> 6;
    const int quad = lane >> 4;
    const int l15  = lane & 15;
    const int wr   = wave >> 1;
    const int wc   = wave & 1;

    f4v acc[4][4] = {};

    if (z == 0) {
        gemm_tile<false>(Xb, WTq, m0, n0, As, Bs, acc);
        #pragma unroll
        for (int j = 0; j < 4; j++) {
            const int n  = n0 + wc * 64 + j * 16 + l15;
            const int h  = n >> 6, dh = n & 63;
            const float bias_n = bq[n] + emo[n];
            #pragma unroll
            for (int i = 0; i < 4; i++) {
                #pragma unroll
                for (int r = 0; r < 4; r++) {
                    const int m = m0 + wr * 64 + i * 16 + quad * 4 + r;
                    const int b = m >> 11, s = m & 2047;
                    q_ws[(((size_t)(b * H_ + h)) * S_ + s) * DH_ + dh] =
                        f2b((acc[i][j][r] + bias_n) * QSCALE_);
                }
            }
        }
    } else if (z == 1) {
        gemm_tile<false>(Xb, WTk, m0, n0, As, Bs, acc);
        #pragma unroll
        for (int j = 0; j < 4; j++) {
            const int n  = n0 + wc * 64 + j * 16 + l15;
            const int h  = n >> 6, dh = n & 63;
            const float bias_n = bk[n];
            #pragma unroll
            for (int i = 0; i < 4; i++) {
                #pragma unroll
                for (int r = 0; r < 4; r++) {
                    const int m = m0 + wr * 64 + i * 16 + quad * 4 + r;
                    const int b = m >> 11, s = m & 2047;
                    k_ws[(((size_t)(b * H_ + h)) * S_ + s) * DH_ + dh] =
                        f2b(acc[i][j][r] + bias_n);
                }
            }
        }
    } else {
        gemm_tile<true>(Xb, WTv, m0, n0, As, Bs, acc);
        #pragma unroll
        for (int j = 0; j < 4; j++) {
            const int m = m0 + wr * 64 + j * 16 + l15;
            const int b = m >> 11, s = m & 2047;
            const float msk = mask[b * S_ + s] ? 1.0f : 0.0f;
            #pragma unroll
            for (int i = 0; i < 4; i++) {
                #pragma unroll
                for (int r = 0; r < 4; r++) {
                    const int n  = n0 + wc * 64 + i * 16 + quad * 4 + r;
                    const int h  = n >> 6, dh = n & 63;
                    v_ws[(((size_t)(b * H_ + h)) * DH_ + dh) * S_ + s] =
                        f2b((acc[i][j][r] + bv[n]) * msk);
                }
            }
        }
    }
}

// ---------------------------------------------------------------------------
// Output projection: 128x128 tile, grid (32, 8). out = ctx @ Wo + bo (fp32).
// ---------------------------------------------------------------------------
__global__ __launch_bounds__(256) void proj_out_kernel(
    const bf16* __restrict__ ctx, const bf16* __restrict__ WTo,
    const float* __restrict__ bo, float* __restrict__ out)
{
    const int m0 = blockIdx.x * 128;
    const int n0 = blockIdx.y * 128;

    __shared__ __align__(16) bf16 As[128 * 64];
    __shared__ __align__(16) bf16 Bs[128 * 64];

    const int t    = threadIdx.x;
    const int lane = t & 63;
    const int wave = t >> 6;
    const int quad = lane >> 4;
    const int l15  = lane & 15;
    const int wr   = wave >> 1;
    const int wc   = wave & 1;

    f4v acc[4][4] = {};
    gemm_tile<false>(ctx, WTo, m0, n0, As, Bs, acc);

    #pragma unroll
    for (int j = 0; j < 4; j++) {
        const int n = n0 + wc * 64 + j * 16 + l15;
        const float bias_n = bo[n];
        #pragma unroll
        for (int i = 0; i < 4; i++) {
            #pragma unroll
            for (int r = 0; r < 4; r++) {
                const int m = m0 + wr * 64 + i * 16 + quad * 4 + r;
                out[(size_t)m * D_ + n] = acc[i][j][r] + bias_n;
            }
        }
    }
}

// ---------------------------------------------------------------------------
// MFMA flash attention (round-15): 32x32x16 MFMA, 32 q/wave, 4 waves,
// grid (B*H=32, S/128=16). K/V staged in LDS (dbuf, swizzled, 1 barrier
// per iter); P kept in registers via cvt_pk_bf16 + permlane32_swap.
//
// Layouts (verified mappings):
//   C/D 32x32: col = lane&31, row = (reg&3) + 8*(reg>>2) + 4*(lane>>5)
//   A 32x16:   row = lane&31, k = (lane>>5)*8 + j
//   B 16x32:   col = lane&31, k = (lane>>5)*8 + j
// QK^T (A=K,B=Q) -> sacc rows=key, cols=q: lane ql and ql+32 hold the SAME
// q, so permlane32_swap (lane i <-> i+32) assembles PV A-frags in-register:
//   w0=pk(p0,p1) w1=pk(p2,p3) w2=pk(p4,p5) w3=pk(p6,p7)
//   swap(w0,w2), swap(w1,w3)  ->  af = {w0,w1,w2,w3}  (16 keys, both halves)
// ---------------------------------------------------------------------------
__global__ __launch_bounds__(256) void attn_kernel(
    const bf16* __restrict__ q_ws, const bf16* __restrict__ k_ws,
    const bf16* __restrict__ v_ws, const bf16* __restrict__ mkbf,
    bf16* __restrict__ ctx)
{
    const int bh = blockIdx.x;
    const int q0 = blockIdx.y * 128;
    const int b  = bh >> 4;
    const int h  = bh & 15;

    __shared__ __align__(16) bf16 k_lds[2][64 * 64];    // [buf][key][dh], swizzled
    __shared__ __align__(16) bf16 vt_lds[2][64 * 64];   // [buf][dh][key], swizzled

    const int t    = threadIdx.x;
    const int wave = t >> 6;
    const int lane = t & 63;
    const int ql   = lane & 31;      // q col (QK C) / key row (A) / dh col (PV C)
    const int hf   = lane >> 5;
    const int swz  = ql & 7;         // fragment-read chunk XOR (row&7)

    // ---- Q as B-operand frags: col q = q0+wave*32+ql, k = kd*16+hf*8 ----
    s8v qf[4];
    #pragma unroll
    for (int kd = 0; kd < 4; kd++)
        qf[kd] = *(const s8v*)(q_ws +
            ((size_t)bh * S_ + q0 + wave * 32 + ql) * DH_ + kd * 16 + hf * 8);

    f16v oacc[2] = {};   // [dt]: rows=q (reg), cols=dh (ql)
    f16v osum    = {};   // denominator, same layout

    const bf16* __restrict__ mbase = mkbf + (size_t)b * S_;

    // staging source indices (256 thr x 16B x 2 = one 64x64 tile)
    int srw[2], scs[2];
    #pragma unroll
    for (int c = 0; c < 2; c++) {
        const int e = c * 2048 + t * 8;
        srw[c] = e >> 6;                          // tile row
        scs[c] = ((e >> 3) & 7) ^ (srw[c] & 7);   // source chunk (swizzled)
    }

    auto stage = [&](int kb0, bf16* kd_, bf16* vd_) {
        #pragma unroll
        for (int c = 0; c < 2; c++) {
            const int e = c * 2048 + t * 8;
            const int r = srw[c], cs = scs[c];
            gl_lds_16B(k_ws + ((size_t)bh * S_ + kb0 + r) * DH_ + cs * 8,
                       kd_ + e);
            gl_lds_16B(v_ws + ((size_t)bh * DH_ + r) * S_ + kb0 + cs * 8,
                       vd_ + e);
        }
    };

    stage(0, k_lds[0], vt_lds[0]);
    __syncthreads();

    int cur = 0;
    for (int kb0 = 0; kb0 < S_; kb0 += 64) {
        // prefetch next tile into other buffer; drained by end-of-iter barrier
        if (kb0 + 64 < S_)
            stage(kb0 + 64, k_lds[cur ^ 1], vt_lds[cur ^ 1]);

        const bf16* __restrict__ kc = k_lds[cur];
        const bf16* __restrict__ vc = vt_lds[cur];

        // ---- S^T = K.Q^T: 2 key-tiles x 4 k-steps of 16 dh ----
        f16v sacc[2] = {};
        __builtin_amdgcn_s_setprio(1);
        #pragma unroll
        for (int kt = 0; kt < 2; kt++) {
            #pragma unroll
            for (int kd = 0; kd < 4; kd++) {
                const s8v kf = *(const s8v*)&kc[(kt * 32 + ql) * 64 +
                                                ((kd * 2 + hf) ^ swz) * 8];
                sacc[kt] = __builtin_amdgcn_mfma_f32_32x32x16_bf16(kf, qf[kd], sacc[kt], 0, 0, 0);
            }
        }
        __builtin_amdgcn_s_setprio(0);

        // ---- per 16-key step: exp2 -> pack -> lane-swap -> PV + denom ----
        #pragma unroll
        for (int kt = 0; kt < 2; kt++) {
            #pragma unroll
            for (int hh = 0; hh < 2; hh++) {
                const int ks = kt * 2 + hh;     // 16-key step within 64
                float p[8];
                #pragma unroll
                for (int j = 0; j < 8; j++)
                    p[j] = exp2f(sacc[kt][hh * 8 + j]);
                unsigned w0 = cvtpk_bf16(p[0], p[1]);
                unsigned w1 = cvtpk_bf16(p[2], p[3]);
                unsigned w2 = cvtpk_bf16(p[4], p[5]);
                unsigned w3 = cvtpk_bf16(p[6], p[7]);
                plswap(w0, w2);
                plswap(w1, w3);
                union { unsigned u[4]; s8v v; } af;
                af.u[0] = w0; af.u[1] = w1; af.u[2] = w2; af.u[3] = w3;

                const s8v mf = *(const s8v*)(mbase + kb0 + ks * 16 + hf * 8);
                __builtin_amdgcn_s_setprio(1);
                osum = __builtin_amdgcn_mfma_f32_32x32x16_bf16(af.v, mf, osum, 0, 0, 0);
                #pragma unroll
                for (int dt = 0; dt < 2; dt++) {
                    const s8v vf = *(const s8v*)&vc[(dt * 32 + ql) * 64 +
                                                    ((ks * 2 + hf) ^ swz) * 8];
                    oacc[dt] = __builtin_amdgcn_mfma_f32_32x32x16_bf16(af.v, vf, oacc[dt], 0, 0, 0);
                }
                __builtin_amdgcn_s_setprio(0);
            }
        }

        // one barrier per iteration: publishes prefetched buffer (vmcnt
        // drain) and protects the just-read buffer from the next staging.
        __syncthreads();
        cur ^= 1;
    }

    // ---- epilogue: reg r -> q row (r&3)+8*(r>>2)+4*hf; col ql = dh ----
    #pragma unroll
    for (int r = 0; r < 16; r++) {
        const float inv = 1.0f / osum[r];
        const int q = q0 + wave * 32 + (r & 3) + 8 * (r >> 2) + 4 * hf;
        #pragma unroll
        for (int dt = 0; dt < 2; dt++)
            ctx[((size_t)b * S_ + q) * D_ + h * DH_ + dt * 32 + ql] =
                f2b(oacc[dt][r] * inv);
    }
}

// ---------------------------------------------------------------------------
extern "C" void kernel_launch(void* const* d_in, const int* in_sizes, int n_in,
                              void* d_out, int out_size, void* d_ws, size_t ws_size,
                              hipStream_t stream) {
    (void)in_sizes; (void)n_in; (void)out_size; (void)ws_size;

    const float* X    = (const float*)d_in[0];
    const int*   mask = (const int*)d_in[1];
    const float* Wq   = (const float*)d_in[2];
    const float* bq   = (const float*)d_in[3];
    const float* Wk   = (const float*)d_in[4];
    const float* bk   = (const float*)d_in[5];
    const float* Wv   = (const float*)d_in[6];
    const float* bv   = (const float*)d_in[7];
    const float* emo  = (const float*)d_in[8];
    const float* Wo   = (const float*)d_in[9];
    const float* bo   = (const float*)d_in[10];
    float* out = (float*)d_out;

    bf16* q_ws = (bf16*)d_ws;                       // [B,H,S,DH]   8 MB
    bf16* k_ws = q_ws + (size_t)BS_ * D_;           // [B,H,S,DH]   8 MB
    bf16* v_ws = k_ws + (size_t)BS_ * D_;           // [B,H,DH,S]   8 MB
    bf16* ctx  = v_ws + (size_t)BS_ * D_;           // [B,S,D]      8 MB
    bf16* Xb   = ctx  + (size_t)BS_ * D_;           // [BS,D]       8 MB
    bf16* WTq  = Xb   + (size_t)BS_ * D_;           // [N,K]        2 MB
    bf16* WTk  = WTq  + (size_t)D_ * K_;
    bf16* WTv  = WTk  + (size_t)D_ * K_;
    bf16* WTo  = WTv  + (size_t)D_ * K_;
    bf16* mkbf = WTo  + (size_t)D_ * K_;            // [B*S] bf16 mask

    hipLaunchKernelGGL(prep_kernel, dim3(5136), dim3(256), 0, stream,
                       X, mask, Wq, Wk, Wv, Wo, Xb, mkbf, WTq, WTk, WTv, WTo);
    hipLaunchKernelGGL(proj_qkv_kernel, dim3(BS_ / 128, D_ / 128, 3), dim3(256), 0, stream,
                       Xb, WTq, bq, WTk, bk, WTv, bv, emo, mask, q_ws, k_ws, v_ws);
    hipLaunchKernelGGL(attn_kernel, dim3(B_ * H_, S_ / 128), dim3(256), 0, stream,
                       q_ws, k_ws, v_ws, mkbf, ctx);
    hipLaunchKernelGGL(proj_out_kernel, dim3(BS_ / 128, D_ / 128), dim3(256), 0, stream,
                       ctx, WTo, bo, out);
}

// Round 5
// 227.928 us; speedup vs baseline: 1.2882x; 1.0274x over previous
//
#include <hip/hip_runtime.h>
#include <hip/hip_bf16.h>

// Problem: AdvancedAttentionLayer  B=2, S=2048, D=1024, H=16, DH=64
// Round 16: attn keeps r15's verified 32x32x16 datapath (LDS-staged K/V,
// in-register P via cvt_pk_bf16 + permlane32_swap) but fixes the occupancy
// cap r15's counters exposed (grid 512 blocks = 2 blocks/CU = 2 waves/SIMD,
// latency-bound: no pipe >25% util). Now 512 threads = 8 waves: wave-group
// g = wave>>2 handles keys [g*1024, g*1024+1024) of the same 128-q tile,
// each group with its own double-buffered K/V LDS (64 KB total -> still
// 2 blocks/CU, now 16 waves/CU = 4 waves/SIMD). Fixed-base softmax makes
// the two KV-half partials exactly additive: group 1 parks oacc/osum in
// the dead K/V LDS after the loop, group 0 merges + divides + writes ctx.
// Prep/proj kernels unchanged.

#define B_  2
#define S_  2048
#define D_  1024
#define K_  1024
#define H_  16
#define DH_ 64
#define BS_ (B_*S_)

typedef __hip_bfloat16 bf16;
typedef __attribute__((ext_vector_type(8))) short s8v;    // 8 bf16 = 4 VGPRs
typedef __attribute__((ext_vector_type(4))) short s4v;    // 4 bf16
typedef __attribute__((ext_vector_type(4))) float f4v;    // 16x16 MFMA C/D
typedef __attribute__((ext_vector_type(16))) float f16v;  // 32x32 MFMA C/D

__device__ __forceinline__ float b2f(bf16 x) { return __bfloat162float(x); }
__device__ __forceinline__ bf16  f2b(float x) { return __float2bfloat16(x); }

__device__ __forceinline__ void gl_lds_16B(const bf16* g, bf16* l) {
    __builtin_amdgcn_global_load_lds(
        (const __attribute__((address_space(1))) unsigned int*)g,
        (__attribute__((address_space(3))) unsigned int*)l, 16, 0, 0);
}

// pack two f32 -> two bf16 in one dword (low = a)
__device__ __forceinline__ unsigned cvtpk_bf16(float a, float b) {
    unsigned r;
    asm("v_cvt_pk_bf16_f32 %0, %1, %2" : "=v"(r) : "v"(a), "v"(b));
    return r;
}
// swap hi-half lanes of a with lo-half lanes of b (lane i <-> lane i+32)
__device__ __forceinline__ void plswap(unsigned &a, unsigned &b) {
    asm("v_permlane32_swap_b32 %0, %1" : "+v"(a), "+v"(b));
}

// 0.125 * log2(e): folded QK^T scale so softmax uses raw exp2
#define QSCALE_ 0.1803368801f

// ---------------------------------------------------------------------------
// Fused prep kernel. Grid 5136 blocks x 256:
//   blocks [0,1024):    W transpose, z = blk>>8 (Wq/Wk/Wv/Wo), 64x64 tiles
//   blocks [1024,5120): X fp32 -> bf16, 1024 elems per block
//   blocks [5120,5136): mask int32 -> bf16 0/1
// ---------------------------------------------------------------------------
__global__ __launch_bounds__(256) void prep_kernel(
    const float* __restrict__ X, const int* __restrict__ mask,
    const float* __restrict__ Wq, const float* __restrict__ Wk,
    const float* __restrict__ Wv, const float* __restrict__ Wo,
    bf16* __restrict__ Xb, bf16* __restrict__ mkbf,
    bf16* __restrict__ WTq, bf16* __restrict__ WTk,
    bf16* __restrict__ WTv, bf16* __restrict__ WTo)
{
    __shared__ float Ls[64][68];
    const int blk = blockIdx.x;
    const int t   = threadIdx.x;

    if (blk < 1024) {
        const int z   = blk >> 8;
        const int t16 = blk & 255;
        const int k0  = (t16 >> 4) * 64;
        const int n0  = (t16 & 15) * 64;
        const float* __restrict__ W = (z == 0) ? Wq : (z == 1) ? Wk : (z == 2) ? Wv : Wo;
        bf16* __restrict__ WT       = (z == 0) ? WTq : (z == 1) ? WTk : (z == 2) ? WTv : WTo;

        const int lr = t >> 4;
        const int lc = (t & 15) * 4;
        #pragma unroll
        for (int i = 0; i < 4; i++) {
            const int k = i * 16 + lr;
            const float4 v = *(const float4*)(W + (size_t)(k0 + k) * K_ + n0 + lc);
            Ls[k][lc + 0] = v.x; Ls[k][lc + 1] = v.y;
            Ls[k][lc + 2] = v.z; Ls[k][lc + 3] = v.w;
        }
        __syncthreads();
        #pragma unroll
        for (int i = 0; i < 4; i++) {
            const int n = i * 16 + lr;
            s4v o;
            #pragma unroll
            for (int j = 0; j < 4; j++) {
                bf16 tb = f2b(Ls[lc + j][n]);
                o[j] = *(short*)&tb;
            }
            *(s4v*)(WT + (size_t)(n0 + n) * K_ + k0 + lc) = o;
        }
    } else if (blk < 5120) {
        const size_t idx = ((size_t)(blk - 1024) * 256 + t) * 4;
        const float4 v = *(const float4*)(X + idx);
        bf16 t0 = f2b(v.x), t1 = f2b(v.y), t2 = f2b(v.z), t3 = f2b(v.w);
        s4v o;
        o[0] = *(short*)&t0; o[1] = *(short*)&t1;
        o[2] = *(short*)&t2; o[3] = *(short*)&t3;
        *(s4v*)(Xb + idx) = o;
    } else {
        const int idx = (blk - 5120) * 256 + t;
        mkbf[idx] = f2b(mask[idx] ? 1.0f : 0.0f);
    }
}

// ---------------------------------------------------------------------------
// MFMA GEMM core, 128x128 tile (m97 structure). SWAPPED -> C^T layout.
// ---------------------------------------------------------------------------
template <bool SWAPPED>
__device__ __forceinline__ void gemm_tile(
    const bf16* __restrict__ A, const bf16* __restrict__ BT,
    int m0, int n0, bf16* As, bf16* Bs, f4v acc[4][4])
{
    const int t    = threadIdx.x;
    const int lane = t & 63;
    const int wave = t >> 6;
    const int quad = lane >> 4;
    const int l15  = lane & 15;
    const int wr   = wave >> 1;
    const int wc   = wave & 1;

    const int sr = t >> 3;
    const int sc = (t & 7) * 8;

    for (int kb = 0; kb < K_; kb += 64) {
        #pragma unroll
        for (int i = 0; i < 4; i++) {
            const int r = i * 32 + sr;
            gl_lds_16B(A  + (size_t)(m0 + r) * K_ + kb + sc, As + r * 64 + sc);
            gl_lds_16B(BT + (size_t)(n0 + r) * K_ + kb + sc, Bs + r * 64 + sc);
        }
        __syncthreads();

        #pragma unroll
        for (int ks = 0; ks < 2; ks++) {
            s8v fA[4], fB[4];
            #pragma unroll
            for (int i = 0; i < 4; i++) {
                fA[i] = *(const s8v*)&As[(wr * 64 + i * 16 + l15) * 64 + ks * 32 + quad * 8];
                fB[i] = *(const s8v*)&Bs[(wc * 64 + i * 16 + l15) * 64 + ks * 32 + quad * 8];
            }
            #pragma unroll
            for (int i = 0; i < 4; i++)
                #pragma unroll
                for (int j = 0; j < 4; j++)
                    acc[i][j] = SWAPPED
                        ? __builtin_amdgcn_mfma_f32_16x16x32_bf16(fB[i], fA[j], acc[i][j], 0, 0, 0)
                        : __builtin_amdgcn_mfma_f32_16x16x32_bf16(fA[i], fB[j], acc[i][j], 0, 0, 0);
        }
        __syncthreads();
    }
}

// ---------------------------------------------------------------------------
// QKV projection via MFMA. Grid (32, 8, 3), block 256.
// ---------------------------------------------------------------------------
__global__ __launch_bounds__(256) void proj_qkv_kernel(
    const bf16* __restrict__ Xb,
    const bf16* __restrict__ WTq, const float* __restrict__ bq,
    const bf16* __restrict__ WTk, const float* __restrict__ bk,
    const bf16* __restrict__ WTv, const float* __restrict__ bv,
    const float* __restrict__ emo, const int* __restrict__ mask,
    bf16* __restrict__ q_ws, bf16* __restrict__ k_ws, bf16* __restrict__ v_ws)
{
    const int m0 = blockIdx.x * 128;
    const int n0 = blockIdx.y * 128;
    const int z  = blockIdx.z;

    __shared__ __align__(16) bf16 As[128 * 64];
    __shared__ __align__(16) bf16 Bs[128 * 64];

    const int t    = threadIdx.x;
    const int lane = t & 63;
    const int wave = t >> 6;
    const int quad = lane >> 4;
    const int l15  = lane & 15;
    const int wr   = wave >> 1;
    const int wc   = wave & 1;

    f4v acc[4][4] = {};

    if (z == 0) {
        gemm_tile<false>(Xb, WTq, m0, n0, As, Bs, acc);
        #pragma unroll
        for (int j = 0; j < 4; j++) {
            const int n  = n0 + wc * 64 + j * 16 + l15;
            const int h  = n >> 6, dh = n & 63;
            const float bias_n = bq[n] + emo[n];
            #pragma unroll
            for (int i = 0; i < 4; i++) {
                #pragma unroll
                for (int r = 0; r < 4; r++) {
                    const int m = m0 + wr * 64 + i * 16 + quad * 4 + r;
                    const int b = m >> 11, s = m & 2047;
                    q_ws[(((size_t)(b * H_ + h)) * S_ + s) * DH_ + dh] =
                        f2b((acc[i][j][r] + bias_n) * QSCALE_);
                }
            }
        }
    } else if (z == 1) {
        gemm_tile<false>(Xb, WTk, m0, n0, As, Bs, acc);
        #pragma unroll
        for (int j = 0; j < 4; j++) {
            const int n  = n0 + wc * 64 + j * 16 + l15;
            const int h  = n >> 6, dh = n & 63;
            const float bias_n = bk[n];
            #pragma unroll
            for (int i = 0; i < 4; i++) {
                #pragma unroll
                for (int r = 0; r < 4; r++) {
                    const int m = m0 + wr * 64 + i * 16 + quad * 4 + r;
                    const int b = m >> 11, s = m & 2047;
                    k_ws[(((size_t)(b * H_ + h)) * S_ + s) * DH_ + dh] =
                        f2b(acc[i][j][r] + bias_n);
                }
            }
        }
    } else {
        gemm_tile<true>(Xb, WTv, m0, n0, As, Bs, acc);
        #pragma unroll
        for (int j = 0; j < 4; j++) {
            const int m = m0 + wr * 64 + j * 16 + l15;
            const int b = m >> 11, s = m & 2047;
            const float msk = mask[b * S_ + s] ? 1.0f : 0.0f;
            #pragma unroll
            for (int i = 0; i < 4; i++) {
                #pragma unroll
                for (int r = 0; r < 4; r++) {
                    const int n  = n0 + wc * 64 + i * 16 + quad * 4 + r;
                    const int h  = n >> 6, dh = n & 63;
                    v_ws[(((size_t)(b * H_ + h)) * DH_ + dh) * S_ + s] =
                        f2b((acc[i][j][r] + bv[n]) * msk);
                }
            }
        }
    }
}

// ---------------------------------------------------------------------------
// Output projection: 128x128 tile, grid (32, 8). out = ctx @ Wo + bo (fp32).
// ---------------------------------------------------------------------------
__global__ __launch_bounds__(256) void proj_out_kernel(
    const bf16* __restrict__ ctx, const bf16* __restrict__ WTo,
    const float* __restrict__ bo, float* __restrict__ out)
{
    const int m0 = blockIdx.x * 128;
    const int n0 = blockIdx.y * 128;

    __shared__ __align__(16) bf16 As[128 * 64];
    __shared__ __align__(16) bf16 Bs[128 * 64];

    const int t    = threadIdx.x;
    const int lane = t & 63;
    const int wave = t >> 6;
    const int quad = lane >> 4;
    const int l15  = lane & 15;
    const int wr   = wave >> 1;
    const int wc   = wave & 1;

    f4v acc[4][4] = {};
    gemm_tile<false>(ctx, WTo, m0, n0, As, Bs, acc);

    #pragma unroll
    for (int j = 0; j < 4; j++) {
        const int n = n0 + wc * 64 + j * 16 + l15;
        const float bias_n = bo[n];
        #pragma unroll
        for (int i = 0; i < 4; i++) {
            #pragma unroll
            for (int r = 0; r < 4; r++) {
                const int m = m0 + wr * 64 + i * 16 + quad * 4 + r;
                out[(size_t)m * D_ + n] = acc[i][j][r] + bias_n;
            }
        }
    }
}

// ---------------------------------------------------------------------------
// MFMA flash attention (round-16): 32x32x16 MFMA, split-KV 8-wave blocks.
// Grid (B*H=32, S/128=16), 512 threads. Wave w: qsub = w&3 (32 q-rows),
// grp = w>>2 (KV half, keys [grp*1024, grp*1024+1024)). Each group has its
// own double-buffered K/V LDS; fixed-base softmax partials are additive,
// merged through LDS at the end. 64 KB LDS -> 2 blocks/CU = 4 waves/SIMD.
//
// Layouts (verified on-device r15):
//   C/D 32x32: col = lane&31, row = (reg&3) + 8*(reg>>2) + 4*(lane>>5)
//   A 32x16:   row = lane&31, k = (lane>>5)*8 + j
//   B 16x32:   col = lane&31, k = (lane>>5)*8 + j
// ---------------------------------------------------------------------------
__global__ __launch_bounds__(512) void attn_kernel(
    const bf16* __restrict__ q_ws, const bf16* __restrict__ k_ws,
    const bf16* __restrict__ v_ws, const bf16* __restrict__ mkbf,
    bf16* __restrict__ ctx)
{
    const int bh = blockIdx.x;
    const int q0 = blockIdx.y * 128;
    const int b  = bh >> 4;
    const int h  = bh & 15;

    // [grp][buf][kv(0=K,1=V)][64*64] -- 65536 B; merge buffer overlays all
    __shared__ __align__(16) bf16 lds[2][2][2][4096];

    const int t    = threadIdx.x;
    const int wave = t >> 6;         // 0..7
    const int qsub = wave & 3;       // q subtile (32 rows)
    const int grp  = wave >> 2;      // KV half
    const int tg   = t & 255;        // thread index within group
    const int lane = t & 63;
    const int ql   = lane & 31;      // q col (QK C) / A row / dh col (PV C)
    const int hf   = lane >> 5;
    const int swz  = ql & 7;         // fragment-read chunk XOR (row&7)

    const int kb_base = grp * 1024;  // this group's key range start

    // ---- Q as B-operand frags: col q = q0+qsub*32+ql, k = kd*16+hf*8 ----
    s8v qf[4];
    #pragma unroll
    for (int kd = 0; kd < 4; kd++)
        qf[kd] = *(const s8v*)(q_ws +
            ((size_t)bh * S_ + q0 + qsub * 32 + ql) * DH_ + kd * 16 + hf * 8);

    f16v oacc[2] = {};   // [dt]: rows=q (reg), cols=dh (ql)
    f16v osum    = {};   // denominator partial, same layout

    const bf16* __restrict__ mbase = mkbf + (size_t)b * S_;

    // staging source indices (256 thr/group x 16B x 2 = one 64x64 tile)
    int srw[2], scs[2];
    #pragma unroll
    for (int c = 0; c < 2; c++) {
        const int e = c * 2048 + tg * 8;
        srw[c] = e >> 6;                          // tile row
        scs[c] = ((e >> 3) & 7) ^ (srw[c] & 7);   // source chunk (swizzled)
    }

    auto stage = [&](int kb_abs, int buf) {
        #pragma unroll
        for (int c = 0; c < 2; c++) {
            const int e = c * 2048 + tg * 8;
            const int r = srw[c], cs = scs[c];
            gl_lds_16B(k_ws + ((size_t)bh * S_ + kb_abs + r) * DH_ + cs * 8,
                       &lds[grp][buf][0][e]);
            gl_lds_16B(v_ws + ((size_t)bh * DH_ + r) * S_ + kb_abs + cs * 8,
                       &lds[grp][buf][1][e]);
        }
    };

    stage(kb_base, 0);
    __syncthreads();

    int cur = 0;
    for (int kb = 0; kb < 1024; kb += 64) {
        // prefetch next tile into other buffer; drained by end-of-iter barrier
        if (kb + 64 < 1024)
            stage(kb_base + kb + 64, cur ^ 1);

        const bf16* __restrict__ kc = &lds[grp][cur][0][0];
        const bf16* __restrict__ vc = &lds[grp][cur][1][0];

        // ---- S^T = K.Q^T: 2 key-tiles x 4 k-steps of 16 dh ----
        f16v sacc[2] = {};
        __builtin_amdgcn_s_setprio(1);
        #pragma unroll
        for (int kt = 0; kt < 2; kt++) {
            #pragma unroll
            for (int kd = 0; kd < 4; kd++) {
                const s8v kf = *(const s8v*)&kc[(kt * 32 + ql) * 64 +
                                                ((kd * 2 + hf) ^ swz) * 8];
                sacc[kt] = __builtin_amdgcn_mfma_f32_32x32x16_bf16(kf, qf[kd], sacc[kt], 0, 0, 0);
            }
        }
        __builtin_amdgcn_s_setprio(0);

        // ---- per 16-key step: exp2 -> pack -> lane-swap -> PV + denom ----
        #pragma unroll
        for (int kt = 0; kt < 2; kt++) {
            #pragma unroll
            for (int hh = 0; hh < 2; hh++) {
                const int ks = kt * 2 + hh;     // 16-key step within 64
                float p[8];
                #pragma unroll
                for (int j = 0; j < 8; j++)
                    p[j] = exp2f(sacc[kt][hh * 8 + j]);
                unsigned w0 = cvtpk_bf16(p[0], p[1]);
                unsigned w1 = cvtpk_bf16(p[2], p[3]);
                unsigned w2 = cvtpk_bf16(p[4], p[5]);
                unsigned w3 = cvtpk_bf16(p[6], p[7]);
                plswap(w0, w2);
                plswap(w1, w3);
                union { unsigned u[4]; s8v v; } af;
                af.u[0] = w0; af.u[1] = w1; af.u[2] = w2; af.u[3] = w3;

                const s8v mf = *(const s8v*)(mbase + kb_base + kb + ks * 16 + hf * 8);
                __builtin_amdgcn_s_setprio(1);
                osum = __builtin_amdgcn_mfma_f32_32x32x16_bf16(af.v, mf, osum, 0, 0, 0);
                #pragma unroll
                for (int dt = 0; dt < 2; dt++) {
                    const s8v vf = *(const s8v*)&vc[(dt * 32 + ql) * 64 +
                                                    ((ks * 2 + hf) ^ swz) * 8];
                    oacc[dt] = __builtin_amdgcn_mfma_f32_32x32x16_bf16(af.v, vf, oacc[dt], 0, 0, 0);
                }
                __builtin_amdgcn_s_setprio(0);
            }
        }

        // one barrier per iteration: publishes prefetched buffer (vmcnt
        // drain) and protects the just-read buffer from the next staging.
        __syncthreads();
        cur ^= 1;
    }

    // ---- merge the two KV-half partials through LDS (buffers now dead) ---
    // mg layout (floats): oacc at [qsub][qrow 32][dh 64] = 8192,
    //                     osum at 8192 + [qsub][qrow 32]  = 128.
    float* mg = (float*)&lds[0][0][0][0];

    if (grp == 1) {
        #pragma unroll
        for (int r = 0; r < 16; r++) {
            const int qrow = (r & 3) + 8 * (r >> 2) + 4 * hf;
            #pragma unroll
            for (int dt = 0; dt < 2; dt++)
                mg[qsub * 2048 + qrow * 64 + dt * 32 + ql] = oacc[dt][r];
            if (ql == 0)
                mg[8192 + qsub * 32 + qrow] = osum[r];
        }
    }
    __syncthreads();
    if (grp == 0) {
        #pragma unroll
        for (int r = 0; r < 16; r++) {
            const int qrow = (r & 3) + 8 * (r >> 2) + 4 * hf;
            const float den = osum[r] + mg[8192 + qsub * 32 + qrow];
            const float inv = 1.0f / den;
            const int q = q0 + qsub * 32 + qrow;
            #pragma unroll
            for (int dt = 0; dt < 2; dt++) {
                const float o = oacc[dt][r] + mg[qsub * 2048 + qrow * 64 + dt * 32 + ql];
                ctx[((size_t)b * S_ + q) * D_ + h * DH_ + dt * 32 + ql] = f2b(o * inv);
            }
        }
    }
}

// ---------------------------------------------------------------------------
extern "C" void kernel_launch(void* const* d_in, const int* in_sizes, int n_in,
                              void* d_out, int out_size, void* d_ws, size_t ws_size,
                              hipStream_t stream) {
    (void)in_sizes; (void)n_in; (void)out_size; (void)ws_size;

    const float* X    = (const float*)d_in[0];
    const int*   mask = (const int*)d_in[1];
    const float* Wq   = (const float*)d_in[2];
    const float* bq   = (const float*)d_in[3];
    const float* Wk   = (const float*)d_in[4];
    const float* bk   = (const float*)d_in[5];
    const float* Wv   = (const float*)d_in[6];
    const float* bv   = (const float*)d_in[7];
    const float* emo  = (const float*)d_in[8];
    const float* Wo   = (const float*)d_in[9];
    const float* bo   = (const float*)d_in[10];
    float* out = (float*)d_out;

    bf16* q_ws = (bf16*)d_ws;                       // [B,H,S,DH]   8 MB
    bf16* k_ws = q_ws + (size_t)BS_ * D_;           // [B,H,S,DH]   8 MB
    bf16* v_ws = k_ws + (size_t)BS_ * D_;           // [B,H,DH,S]   8 MB
    bf16* ctx  = v_ws + (size_t)BS_ * D_;           // [B,S,D]      8 MB
    bf16* Xb   = ctx  + (size_t)BS_ * D_;           // [BS,D]       8 MB
    bf16* WTq  = Xb   + (size_t)BS_ * D_;           // [N,K]        2 MB
    bf16* WTk  = WTq  + (size_t)D_ * K_;
    bf16* WTv  = WTk  + (size_t)D_ * K_;
    bf16* WTo  = WTv  + (size_t)D_ * K_;
    bf16* mkbf = WTo  + (size_t)D_ * K_;            // [B*S] bf16 mask

    hipLaunchKernelGGL(prep_kernel, dim3(5136), dim3(256), 0, stream,
                       X, mask, Wq, Wk, Wv, Wo, Xb, mkbf, WTq, WTk, WTv, WTo);
    hipLaunchKernelGGL(proj_qkv_kernel, dim3(BS_ / 128, D_ / 128, 3), dim3(256), 0, stream,
                       Xb, WTq, bq, WTk, bk, WTv, bv, emo, mask, q_ws, k_ws, v_ws);
    hipLaunchKernelGGL(attn_kernel, dim3(B_ * H_, S_ / 128), dim3(512), 0, stream,
                       q_ws, k_ws, v_ws, mkbf, ctx);
    hipLaunchKernelGGL(proj_out_kernel, dim3(BS_ / 128, D_ / 128), dim3(256), 0, stream,
                       ctx, WTo, bo, out);
}